// Round 7
// baseline (208.557 us; speedup 1.0000x reference)
//
#include <hip/hip_runtime.h>
#include <math.h>

#define N_Q 20000
#define KK 48
#define CC 64
#define FFD 256

// ws f32 offsets
#define TW_WOT   0        // 4096 f32: WoT[j*64+c] = out_w[c*64+j]        (attn)
#define TW_WVT   4096     // 4096 f32: WvT[cp*64+c] = in_w[(128+c)*64+cp] (attn)
// bf16 (ushort) offsets into ws viewed as ushort*
#define U_L1     16384    // 16384 us: lin1_w row-major bf16 [256][64]
#define U_L2     32768    // 16384 us: lin2_w row-major bf16 [64][256]
#define U_OL     49152    // 4096  us: outl_w row-major bf16 [64][64]
#define U_WQ     53248    // 4096  us: Wq (in_w rows 0..63) bf16 [64][64]
#define U_WK     57344    // 8192  us: WkT per head [h][j][k32], k>=16 zero
#define ST_OFF   32768    // 256 f32: sum1,sumsq1,sum2,sumsq2
#define M_OFF    33024    // bf16 M_all[n][h*64+j], 20000*256 ushorts
#define VF_OFF   2593024  // bf16 vfeat table, 80000*64 ushorts

typedef short bf16x8 __attribute__((ext_vector_type(8)));
typedef float f32x4  __attribute__((ext_vector_type(4)));

__device__ __forceinline__ unsigned f2bf(float f) {
    unsigned u = __float_as_uint(f);
    return (u + 0x7fffu + ((u >> 16) & 1u)) >> 16;          // RNE to bf16
}
__device__ __forceinline__ unsigned pk2(float a, float b) {
    return f2bf(a) | (f2bf(b) << 16);
}
__device__ __forceinline__ float bflo(unsigned u) { return __uint_as_float(u << 16); }
__device__ __forceinline__ float bfhi(unsigned u) { return __uint_as_float(u & 0xffff0000u); }
__device__ __forceinline__ bf16x8 ldfrag(const unsigned short* p) {
    return *(const bf16x8*)p;
}

// ---------------------------------------------------------------------------
// prep_all: bf16 vfeat table + plain row-major bf16 weight copies + fp32
// attn transposes + stats zero. All writes coalesced. grid 5225 x 256.
// ---------------------------------------------------------------------------
__global__ void prep_all(const float* __restrict__ in_w,
                         const float* __restrict__ out_w,
                         const float* __restrict__ lin1_w,
                         const float* __restrict__ lin2_w,
                         const float* __restrict__ outl_w,
                         const float* __restrict__ vfeat,
                         float* __restrict__ tw,
                         unsigned short* __restrict__ wsu,
                         unsigned short* __restrict__ vfeat_bf,
                         float* __restrict__ stats)
{
    int t = blockIdx.x * 256 + threadIdx.x;
    if (t < 1280000) {                          // vfeat -> bf16 (4 elems/thread)
        float4 v = ((const float4*)vfeat)[t];
        uint2 p; p.x = pk2(v.x, v.y); p.y = pk2(v.z, v.w);
        ((uint2*)vfeat_bf)[t] = p;
        return;
    }
    int u = t - 1280000;
    if (u < 4096) {
        int c = u >> 6, j = u & 63;
        tw[TW_WOT + j*64 + c] = out_w[c*64 + j];
    } else if (u < 8192) {
        int i = u - 4096, cp = i >> 6, c = i & 63;
        tw[TW_WVT + cp*64 + c] = in_w[(128 + c)*64 + cp];
    } else if (u < 24576) {
        int i = u - 8192;
        wsu[U_L1 + i] = (unsigned short)f2bf(lin1_w[i]);
    } else if (u < 40960) {
        int i = u - 24576;
        wsu[U_L2 + i] = (unsigned short)f2bf(lin2_w[i]);
    } else if (u < 45056) {
        int i = u - 40960;
        wsu[U_OL + i] = (unsigned short)f2bf(outl_w[i]);
    } else if (u < 49152) {
        int i = u - 45056;
        wsu[U_WQ + i] = (unsigned short)f2bf(in_w[i]);      // rows 0..63 = Wq
    } else if (u < 57344) {
        int v = u - 49152;
        int h = v >> 11, rem = v & 2047, j = rem >> 5, k = rem & 31;
        unsigned short val = 0;
        if (k < 16) val = (unsigned short)f2bf(in_w[(64 + h*16 + k)*64 + j]);
        wsu[U_WK + v] = val;
    } else if (u < 57600) {
        stats[u - 57344] = 0.0f;
    }
}

// ---------------------------------------------------------------------------
// m_kernel (MFMA): 80 queries/block, 250 blocks. qf=relu(qc@qw^T+qb) staged
// bf16 -> q GEMM (wave w owns cols w*16..+15) -> per-head M GEMM (head = w).
// B-fragments loaded directly from row-major bf16 global (16B per lane).
// M_all layout: [n][h*64+j] (h-major, quad-contiguous stores).
// ---------------------------------------------------------------------------
__global__ __launch_bounds__(256) void m_kernel(
    const float* __restrict__ qcoord, const float* __restrict__ q_w,
    const float* __restrict__ q_b, const float* __restrict__ in_b,
    const unsigned short* __restrict__ wsu, unsigned short* __restrict__ M_all)
{
    __shared__ __align__(16) unsigned short sQF[80*72];
    __shared__ __align__(16) unsigned short sQ[80*72];
    int t = threadIdx.x, base = blockIdx.x * 80;
    int colq = (t*4) & 63;
    float qwv[12];
    #pragma unroll
    for (int j = 0; j < 12; ++j) qwv[j] = q_w[colq*3 + j];
    float4 qb4 = *(const float4*)&q_b[colq];
    #pragma unroll
    for (int i = 0; i < 5; ++i) {
        int e = i*1024 + t*4, r = e >> 6, n = base + r;
        float c0 = qcoord[n*3], c1 = qcoord[n*3+1], c2 = qcoord[n*3+2];
        float f0 = fmaxf(fmaf(qwv[2],  c2, fmaf(qwv[1],  c1, fmaf(qwv[0], c0, qb4.x))), 0.f);
        float f1 = fmaxf(fmaf(qwv[5],  c2, fmaf(qwv[4],  c1, fmaf(qwv[3], c0, qb4.y))), 0.f);
        float f2 = fmaxf(fmaf(qwv[8],  c2, fmaf(qwv[7],  c1, fmaf(qwv[6], c0, qb4.z))), 0.f);
        float f3 = fmaxf(fmaf(qwv[11], c2, fmaf(qwv[10], c1, fmaf(qwv[9], c0, qb4.w))), 0.f);
        uint2 p; p.x = pk2(f0, f1); p.y = pk2(f2, f3);
        *(uint2*)&sQF[r*72 + colq] = p;
    }
    int w = t >> 6, lane = t & 63, l16 = lane & 15, quad = lane >> 4;
    // B-frags straight from global bf16 row-major
    bf16x8 qbf[2], kbf[4];
    #pragma unroll
    for (int ks = 0; ks < 2; ++ks)
        qbf[ks] = ldfrag(&wsu[U_WQ + (w*16 + l16)*64 + ks*32 + quad*8]);
    #pragma unroll
    for (int nb = 0; nb < 4; ++nb)
        kbf[nb] = ldfrag(&wsu[U_WK + w*2048 + (nb*16 + l16)*32 + quad*8]);
    __syncthreads();

    int cq = w*16 + l16;
    float bq = in_b[cq];
    #pragma unroll
    for (int mb = 0; mb < 5; ++mb) {
        bf16x8 a0 = ldfrag(&sQF[(mb*16 + l16)*72 + quad*8]);
        bf16x8 a1 = ldfrag(&sQF[(mb*16 + l16)*72 + 32 + quad*8]);
        f32x4 acc = {0.f, 0.f, 0.f, 0.f};
        acc = __builtin_amdgcn_mfma_f32_16x16x32_bf16(a0, qbf[0], acc, 0, 0, 0);
        acc = __builtin_amdgcn_mfma_f32_16x16x32_bf16(a1, qbf[1], acc, 0, 0, 0);
        #pragma unroll
        for (int reg = 0; reg < 4; ++reg) {
            int row = mb*16 + quad*4 + reg;
            sQ[row*72 + cq] = (unsigned short)f2bf((acc[reg] + bq) * 0.25f);
        }
    }
    // per-head M GEMM: head h = w reads exactly the cols it wrote (in-order)
    #pragma unroll
    for (int mb = 0; mb < 5; ++mb) {
        bf16x8 a = {0,0,0,0,0,0,0,0};
        if (quad < 2) a = ldfrag(&sQ[(mb*16 + l16)*72 + w*16 + quad*8]);
        f32x4 acc[4];
        #pragma unroll
        for (int nb = 0; nb < 4; ++nb) {
            f32x4 z = {0.f, 0.f, 0.f, 0.f};
            acc[nb] = __builtin_amdgcn_mfma_f32_16x16x32_bf16(a, kbf[nb], z, 0, 0, 0);
        }
        #pragma unroll
        for (int nb = 0; nb < 4; ++nb)
            #pragma unroll
            for (int reg = 0; reg < 4; ++reg) {
                int r = base + mb*16 + quad*4 + reg, j = nb*16 + l16;
                M_all[(size_t)r*256 + w*64 + j] = (unsigned short)f2bf(acc[nb][reg]);
            }
    }
}

// ---------------------------------------------------------------------------
// attn: one wave/query. bf16 gather (8B/lane) -> bf16 KF in LDS (7.9 KB
// total => 20 blocks/CU). sM in [h][j] layout: float4 broadcast reads.
// Factored scores, softmax, T=P@KF, ctx, att. Barrier-free single wave.
// ---------------------------------------------------------------------------
__global__ __launch_bounds__(64, 4) void attn_kernel(
    const unsigned short* __restrict__ vfeat_bf, const float* __restrict__ vcoord,
    const float* __restrict__ qcoord, const int* __restrict__ kidx,
    const float* __restrict__ kpos_w, const float* __restrict__ kpos_b,
    const float* __restrict__ in_b, const float* __restrict__ out_b,
    const float* __restrict__ tw, const unsigned short* __restrict__ M_all,
    float* __restrict__ att_out)
{
    __shared__ __align__(16) unsigned short skf[KK*72];  // 6912 B, bf16, pitch 72
    __shared__ __align__(16) float reg1[256];            // sM | sP | sctx
    int n = blockIdx.x, c = threadIdx.x;
    int l16 = c & 15, h = c >> 4;
    float* sM   = reg1;          // [h*64+j], dead after score loop
    float* sP   = reg1;          // 192 f, written post-softmax
    float* sctx = reg1 + 192;    // 64 f
    float* sT   = (float*)skf;   // 4*65 f, aliases skf (dead after T loop)

    // stage M (bf16 -> f32), h-major: lane c covers head c>>4, j = 4*(c&15)..+3
    {
        uint2 mu = ((const uint2*)(M_all + (size_t)n*256))[c];
        float4 mf;
        mf.x = bflo(mu.x); mf.y = bfhi(mu.x);
        mf.z = bflo(mu.y); mf.w = bfhi(mu.y);
        *(float4*)&sM[h*64 + 4*l16] = mf;
    }

    float qc0 = qcoord[n*3+0], qc1 = qcoord[n*3+1], qc2 = qcoord[n*3+2];

    // lanes 0..47: key index + relative coords
    int kread = c < 48 ? c : 47;
    int idxv = kidx[(size_t)n*KK + kread];
    int sfe = idxv < 0 ? 0 : idxv;
    float rl0 = vcoord[sfe*3+0] - qc0;
    float rl1 = vcoord[sfe*3+1] - qc1;
    float rl2 = vcoord[sfe*3+2] - qc2;

    // kpos params for this lane's 4 channels (j = 4*l16 + 0..3)
    float4 wA  = *(const float4*)(kpos_w + 12*l16 + 0);
    float4 wB  = *(const float4*)(kpos_w + 12*l16 + 4);
    float4 wC  = *(const float4*)(kpos_w + 12*l16 + 8);
    float4 kb4 = *(const float4*)(kpos_b + 4*l16);

    // ---- issue all 12 gather loads (8B/lane: 4 bf16 channels) ----
    uint2 fv[12];
    #pragma unroll
    for (int i = 0; i < 12; ++i) {
        int row = 4*i + h;
        int si = __shfl(idxv, row);
        si = si < 0 ? 0 : si;
        fv[i] = *(const uint2*)(vfeat_bf + (size_t)si*64 + 4*l16);
    }
    // ---- consume: unpack, add positional encoding, repack to bf16 LDS ----
    #pragma unroll
    for (int i = 0; i < 12; ++i) {
        int row = 4*i + h;
        float rr0 = __shfl(rl0, row), rr1 = __shfl(rl1, row), rr2 = __shfl(rl2, row);
        float g0 = bflo(fv[i].x), g1 = bfhi(fv[i].x);
        float g2 = bflo(fv[i].y), g3 = bfhi(fv[i].y);
        g0 += fmaxf(fmaf(wA.x, rr0, fmaf(wA.y, rr1, fmaf(wA.z, rr2, kb4.x))), 0.0f);
        g1 += fmaxf(fmaf(wA.w, rr0, fmaf(wB.x, rr1, fmaf(wB.y, rr2, kb4.y))), 0.0f);
        g2 += fmaxf(fmaf(wB.z, rr0, fmaf(wB.w, rr1, fmaf(wC.x, rr2, kb4.z))), 0.0f);
        g3 += fmaxf(fmaf(wC.y, rr0, fmaf(wC.z, rr1, fmaf(wC.w, rr2, kb4.w))), 0.0f);
        uint2 p; p.x = pk2(g0, g1); p.y = pk2(g2, g3);
        *(uint2*)&skf[row*72 + 4*l16] = p;
    }

    // ---- scores: lane (l16,h) computes S[h, l16], S[h, l16+16], S[h, l16+32]
    int i0 = __shfl(idxv, l16), i1 = __shfl(idxv, l16 + 16), i2 = __shfl(idxv, l16 + 32);
    float S0 = 0, S1 = 0, S2 = 0;
    #pragma unroll
    for (int j8 = 0; j8 < 8; ++j8) {
        uint2 A = *(const uint2*)&skf[ l16       *72 + 8*j8];
        uint2 A2= *(const uint2*)&skf[ l16       *72 + 8*j8 + 4];
        uint2 B = *(const uint2*)&skf[(l16 + 16) *72 + 8*j8];
        uint2 B2= *(const uint2*)&skf[(l16 + 16) *72 + 8*j8 + 4];
        uint2 D = *(const uint2*)&skf[(l16 + 32) *72 + 8*j8];
        uint2 D2= *(const uint2*)&skf[(l16 + 32) *72 + 8*j8 + 4];
        float4 mA = *(const float4*)&sM[h*64 + 8*j8];       // broadcast
        float4 mB = *(const float4*)&sM[h*64 + 8*j8 + 4];
        #pragma unroll
        for (int jj = 0; jj < 8; ++jj) {
            unsigned ua = (jj < 4) ? ((jj < 2) ? A.x : A.y) : ((jj < 6) ? A2.x : A2.y);
            unsigned ub = (jj < 4) ? ((jj < 2) ? B.x : B.y) : ((jj < 6) ? B2.x : B2.y);
            unsigned ud = (jj < 4) ? ((jj < 2) ? D.x : D.y) : ((jj < 6) ? D2.x : D2.y);
            float av = (jj & 1) ? bfhi(ua) : bflo(ua);
            float bv = (jj & 1) ? bfhi(ub) : bflo(ub);
            float dv = (jj & 1) ? bfhi(ud) : bflo(ud);
            float m  = (jj < 4) ? ((jj < 2) ? ((jj & 1) ? mA.y : mA.x) : ((jj & 1) ? mA.w : mA.z))
                                : ((jj < 6) ? ((jj & 1) ? mB.y : mB.x) : ((jj & 1) ? mB.w : mB.z));
            S0 = fmaf(av, m, S0);
            S1 = fmaf(bv, m, S1);
            S2 = fmaf(dv, m, S2);
        }
    }
    if (i0 < 0) S0 = -INFINITY;
    if (i1 < 0) S1 = -INFINITY;
    if (i2 < 0) S2 = -INFINITY;

    // ---- softmax across the 16 lanes of head h ----
    float mx = fmaxf(S0, fmaxf(S1, S2));
    #pragma unroll
    for (int off = 8; off >= 1; off >>= 1) mx = fmaxf(mx, __shfl_xor(mx, off, 16));
    float e0 = __expf(S0 - mx), e1 = __expf(S1 - mx), e2 = __expf(S2 - mx);
    float es = e0 + e1 + e2;
    #pragma unroll
    for (int off = 8; off >= 1; off >>= 1) es += __shfl_xor(es, off, 16);
    float rinv = 1.0f / es;
    sP[ l16       *4 + h] = e0 * rinv;
    sP[(l16 + 16) *4 + h] = e1 * rinv;
    sP[(l16 + 32) *4 + h] = e2 * rinv;

    // ---- T[h', c] = sum_k P[h',k] * KF[k,c] ----
    float T0 = 0, T1 = 0, T2 = 0, T3 = 0;
    #pragma unroll 8
    for (int k = 0; k < KK; ++k) {
        float kf = __uint_as_float(((unsigned)skf[k*72 + c]) << 16);
        float4 p = *(const float4*)&sP[k*4];
        T0 = fmaf(p.x, kf, T0); T1 = fmaf(p.y, kf, T1);
        T2 = fmaf(p.z, kf, T2); T3 = fmaf(p.w, kf, T3);
    }
    sT[0*65 + c] = T0; sT[1*65 + c] = T1; sT[2*65 + c] = T2; sT[3*65 + c] = T3;

    // ---- ctx[c] = bv[c] + sum_cp T[h(c), cp] * Wv[c, cp] ----
    const float* WvT = tw + TW_WVT;
    float ctx = in_b[128 + c];
    #pragma unroll 8
    for (int cp = 0; cp < 64; ++cp)
        ctx = fmaf(sT[h*65 + cp], WvT[cp*64 + c], ctx);
    sctx[c] = ctx;

    // ---- att[c] = bo[c] + sum_j ctx[j] * Wo[c, j] ----
    const float* WoT = tw + TW_WOT;
    float att = out_b[c];
    #pragma unroll 8
    for (int j = 0; j < 64; ++j)
        att = fmaf(sctx[j], WoT[j*64 + c], att);
    att_out[(size_t)n*64 + c] = att;
}

// ---------------------------------------------------------------------------
// ffn (MFMA): y = att + lin2(relu(lin1(att))), in place; BN1 stats.
// 48 queries/block, 417 blocks, guarded tail. LDS 32.3 KB -> 4 blocks/CU.
// B-fragments loaded directly from row-major bf16 global.
// ---------------------------------------------------------------------------
__global__ __launch_bounds__(256) void ffn_kernel(
    const unsigned short* __restrict__ wsu, const float* __restrict__ lin1_b,
    const float* __restrict__ lin2_b, float* __restrict__ att_y,
    float* __restrict__ sum1, float* __restrict__ sumsq1)
{
    __shared__ __align__(16) unsigned short sA[48*72];
    __shared__ __align__(16) unsigned short sH[48*264];
    int t = threadIdx.x, base = blockIdx.x * 48;
    #pragma unroll
    for (int i = 0; i < 3; ++i) {
        int e = i*1024 + t*4, r = e >> 6, col = e & 63;
        int n = base + r;
        uint2 p = {0u, 0u};
        if (n < N_Q) {
            float4 v = *(const float4*)&att_y[(size_t)n*64 + col];
            p.x = pk2(v.x, v.y); p.y = pk2(v.z, v.w);
        }
        *(uint2*)&sA[r*72 + col] = p;
    }
    int w = t >> 6, lane = t & 63, l16 = lane & 15, quad = lane >> 4;
    bf16x8 b1f[2][4], b2f[8];
    #pragma unroll
    for (int ks = 0; ks < 2; ++ks)
        #pragma unroll
        for (int nb = 0; nb < 4; ++nb)
            b1f[ks][nb] = ldfrag(&wsu[U_L1 + (w*64 + nb*16 + l16)*64 + ks*32 + quad*8]);
    #pragma unroll
    for (int ks = 0; ks < 8; ++ks)
        b2f[ks] = ldfrag(&wsu[U_L2 + (w*16 + l16)*256 + ks*32 + quad*8]);
    __syncthreads();

    #pragma unroll
    for (int mb = 0; mb < 3; ++mb) {
        bf16x8 a0 = ldfrag(&sA[(mb*16 + l16)*72 + quad*8]);
        bf16x8 a1 = ldfrag(&sA[(mb*16 + l16)*72 + 32 + quad*8]);
        #pragma unroll
        for (int nb = 0; nb < 4; ++nb) {
            f32x4 acc = {0.f, 0.f, 0.f, 0.f};
            acc = __builtin_amdgcn_mfma_f32_16x16x32_bf16(a0, b1f[0][nb], acc, 0, 0, 0);
            acc = __builtin_amdgcn_mfma_f32_16x16x32_bf16(a1, b1f[1][nb], acc, 0, 0, 0);
            int f = w*64 + nb*16 + l16;
            float bias = lin1_b[f];
            #pragma unroll
            for (int reg = 0; reg < 4; ++reg) {
                int row = mb*16 + quad*4 + reg;
                sH[row*264 + f] = (unsigned short)f2bf(fmaxf(acc[reg] + bias, 0.0f));
            }
        }
    }
    __syncthreads();

    int c = w*16 + l16;
    float lb2 = lin2_b[c];
    float s = 0.f, ss = 0.f;
    #pragma unroll
    for (int mb = 0; mb < 3; ++mb) {
        f32x4 acc = {0.f, 0.f, 0.f, 0.f};
        #pragma unroll
        for (int ks = 0; ks < 8; ++ks) {
            bf16x8 a = ldfrag(&sH[(mb*16 + l16)*264 + ks*32 + quad*8]);
            acc = __builtin_amdgcn_mfma_f32_16x16x32_bf16(a, b2f[ks], acc, 0, 0, 0);
        }
        #pragma unroll
        for (int reg = 0; reg < 4; ++reg) {
            int r = base + mb*16 + quad*4 + reg;
            if (r < N_Q) {
                float y = att_y[(size_t)r*64 + c] + lb2 + acc[reg];
                att_y[(size_t)r*64 + c] = y;
                s += y; ss = fmaf(y, y, ss);
            }
        }
    }
    s  += __shfl_xor(s, 16);  s  += __shfl_xor(s, 32);
    ss += __shfl_xor(ss, 16); ss += __shfl_xor(ss, 32);
    if (lane < 16) {
        atomicAdd(&sum1[c], s);
        atomicAdd(&sumsq1[c], ss);
    }
}

// ---------------------------------------------------------------------------
// linout (MFMA): xn = bn1(y) staged bf16; z = xn @ Ol^T + ob -> d_out; BN2
// stats. 48 rows/block, 417 blocks, guarded.
// ---------------------------------------------------------------------------
__global__ __launch_bounds__(256) void linout_kernel(
    const unsigned short* __restrict__ wsu, const float* __restrict__ outl_b,
    const float* __restrict__ norm_g, const float* __restrict__ norm_b,
    const float* __restrict__ sum1, const float* __restrict__ sumsq1,
    const float* __restrict__ y, float* __restrict__ z_out,
    float* __restrict__ sum2, float* __restrict__ sumsq2)
{
    __shared__ __align__(16) unsigned short sX[48*72];
    int t = threadIdx.x, base = blockIdx.x * 48;
    int colq = (t*4) & 63;
    const float invN = 1.0f / 20000.0f;
    float4 sm = *(const float4*)&sum1[colq];
    float4 sq = *(const float4*)&sumsq1[colq];
    float4 g  = *(const float4*)&norm_g[colq];
    float4 bb = *(const float4*)&norm_b[colq];
    float mu0 = sm.x*invN, mu1 = sm.y*invN, mu2 = sm.z*invN, mu3 = sm.w*invN;
    float a0 = g.x / sqrtf(fmaf(-mu0, mu0, sq.x*invN) + 1e-5f);
    float a1 = g.y / sqrtf(fmaf(-mu1, mu1, sq.y*invN) + 1e-5f);
    float a2 = g.z / sqrtf(fmaf(-mu2, mu2, sq.z*invN) + 1e-5f);
    float a3 = g.w / sqrtf(fmaf(-mu3, mu3, sq.w*invN) + 1e-5f);
    float b0 = fmaf(-mu0, a0, bb.x), b1 = fmaf(-mu1, a1, bb.y);
    float b2 = fmaf(-mu2, a2, bb.z), b3 = fmaf(-mu3, a3, bb.w);
    #pragma unroll
    for (int i = 0; i < 3; ++i) {
        int e = i*1024 + t*4, r = e >> 6;
        int n = base + r;
        uint2 p = {0u, 0u};
        if (n < N_Q) {
            float4 v = *(const float4*)&y[(size_t)n*64 + colq];
            p.x = pk2(fmaf(v.x, a0, b0), fmaf(v.y, a1, b1));
            p.y = pk2(fmaf(v.z, a2, b2), fmaf(v.w, a3, b3));
        }
        *(uint2*)&sX[r*72 + colq] = p;
    }
    int w = t >> 6, lane = t & 63, l16 = lane & 15, quad = lane >> 4;
    bf16x8 obf[2];
    #pragma unroll
    for (int ks = 0; ks < 2; ++ks)
        obf[ks] = ldfrag(&wsu[U_OL + (w*16 + l16)*64 + ks*32 + quad*8]);
    __syncthreads();

    int co = w*16 + l16;
    float ob = outl_b[co];
    float s = 0.f, ss = 0.f;
    #pragma unroll
    for (int mb = 0; mb < 3; ++mb) {
        bf16x8 x0 = ldfrag(&sX[(mb*16 + l16)*72 + quad*8]);
        bf16x8 x1 = ldfrag(&sX[(mb*16 + l16)*72 + 32 + quad*8]);
        f32x4 acc = {0.f, 0.f, 0.f, 0.f};
        acc = __builtin_amdgcn_mfma_f32_16x16x32_bf16(x0, obf[0], acc, 0, 0, 0);
        acc = __builtin_amdgcn_mfma_f32_16x16x32_bf16(x1, obf[1], acc, 0, 0, 0);
        #pragma unroll
        for (int reg = 0; reg < 4; ++reg) {
            int r = base + mb*16 + quad*4 + reg;
            if (r < N_Q) {
                float zv = acc[reg] + ob;
                z_out[(size_t)r*64 + co] = zv;
                s += zv; ss = fmaf(zv, zv, ss);
            }
        }
    }
    s  += __shfl_xor(s, 16);  s  += __shfl_xor(s, 32);
    ss += __shfl_xor(ss, 16); ss += __shfl_xor(ss, 32);
    if (lane < 16) {
        atomicAdd(&sum2[co], s);
        atomicAdd(&sumsq2[co], ss);
    }
}

// ---------------------------------------------------------------------------
// out = relu(bn2(z)) in place.
// ---------------------------------------------------------------------------
__global__ void final_kernel(float* __restrict__ z,
    const float* __restrict__ sum2, const float* __restrict__ sumsq2,
    const float* __restrict__ obn_g, const float* __restrict__ obn_b)
{
    int i = blockIdx.x*blockDim.x + threadIdx.x;
    if (i >= N_Q*64/4) return;
    int o4 = (i*4) & 63;
    float4 sm = *(const float4*)&sum2[o4];
    float4 sq = *(const float4*)&sumsq2[o4];
    float4 g  = *(const float4*)&obn_g[o4];
    float4 b  = *(const float4*)&obn_b[o4];
    const float invN = 1.0f / 20000.0f;
    float mux = sm.x*invN, muy = sm.y*invN, muz = sm.z*invN, muw = sm.w*invN;
    float ax = g.x / sqrtf(fmaf(-mux, mux, sq.x*invN) + 1e-5f);
    float ay = g.y / sqrtf(fmaf(-muy, muy, sq.y*invN) + 1e-5f);
    float az = g.z / sqrtf(fmaf(-muz, muz, sq.z*invN) + 1e-5f);
    float aw = g.w / sqrtf(fmaf(-muw, muw, sq.w*invN) + 1e-5f);
    float4 v = ((float4*)z)[i];
    v.x = fmaxf(fmaf(v.x - mux, ax, b.x), 0.0f);
    v.y = fmaxf(fmaf(v.y - muy, ay, b.y), 0.0f);
    v.z = fmaxf(fmaf(v.z - muz, az, b.z), 0.0f);
    v.w = fmaxf(fmaf(v.w - muw, aw, b.w), 0.0f);
    ((float4*)z)[i] = v;
}

extern "C" void kernel_launch(void* const* d_in, const int* in_sizes, int n_in,
                              void* d_out, int out_size, void* d_ws, size_t ws_size,
                              hipStream_t stream)
{
    const float* vfeat  = (const float*)d_in[0];
    const float* vcoord = (const float*)d_in[1];
    const float* qcoord = (const float*)d_in[2];
    const int*   kidx   = (const int*)d_in[3];
    const float* q_w    = (const float*)d_in[4];
    const float* q_b    = (const float*)d_in[5];
    const float* kpos_w = (const float*)d_in[6];
    const float* kpos_b = (const float*)d_in[7];
    const float* in_w   = (const float*)d_in[8];
    const float* in_b   = (const float*)d_in[9];
    const float* out_w  = (const float*)d_in[10];
    const float* out_b  = (const float*)d_in[11];
    const float* lin1_w = (const float*)d_in[12];
    const float* lin1_b = (const float*)d_in[13];
    const float* lin2_w = (const float*)d_in[14];
    const float* lin2_b = (const float*)d_in[15];
    const float* norm_g = (const float*)d_in[16];
    const float* norm_b = (const float*)d_in[17];
    const float* outl_w = (const float*)d_in[18];
    const float* outl_b = (const float*)d_in[19];
    const float* obn_g  = (const float*)d_in[20];
    const float* obn_b  = (const float*)d_in[21];

    float* ws = (float*)d_ws;
    float* tw = ws;
    unsigned short* wsu = (unsigned short*)ws;
    float* stats = ws + ST_OFF;
    float* sum1 = stats, *sumsq1 = stats + 64, *sum2 = stats + 128, *sumsq2 = stats + 192;
    unsigned short* M_all = (unsigned short*)(ws + M_OFF);
    unsigned short* vfeat_bf = (unsigned short*)(ws + VF_OFF);
    float* xd = (float*)d_out;    // att -> y -> z -> out, all in place

    prep_all<<<5225, 256, 0, stream>>>(in_w, out_w, lin1_w, lin2_w, outl_w,
                                       vfeat, tw, wsu, vfeat_bf, stats);
    m_kernel<<<250, 256, 0, stream>>>(qcoord, q_w, q_b, in_b, wsu, M_all);
    attn_kernel<<<N_Q, 64, 0, stream>>>(vfeat_bf, vcoord, qcoord, kidx, kpos_w, kpos_b,
                                        in_b, out_b, tw, M_all, xd);
    ffn_kernel<<<417, 256, 0, stream>>>(wsu, lin1_b, lin2_b, xd, sum1, sumsq1);
    linout_kernel<<<417, 256, 0, stream>>>(wsu, outl_b, norm_g, norm_b, sum1, sumsq1,
                                           xd, xd, sum2, sumsq2);
    final_kernel<<<1250, 256, 0, stream>>>(xd, sum2, sumsq2, obn_g, obn_b);
}